// Round 3
// baseline (1144.753 us; speedup 1.0000x reference)
//
#include <hip/hip_runtime.h>
#include <stdint.h>

#define T_TOKENS 8192
#define DDIM 2048
#define FDIM 4096
#define NEXP 8
#define MAXTILES 72   // 128-row tiles: max 64 full + 7 ragged < 72

typedef __attribute__((ext_vector_type(8))) short bf16x8;
typedef __attribute__((ext_vector_type(4))) float f32x4;

// round-to-nearest-even fp32 -> bf16 (finite inputs)
__device__ __forceinline__ unsigned short f2bf(float f) {
  unsigned int u = __float_as_uint(f);
  unsigned int r = (u + 0x7FFFu + ((u >> 16) & 1u)) >> 16;
  return (unsigned short)r;
}

__global__ void k_assign(const float* __restrict__ logits,
                         int* __restrict__ assign,
                         int* __restrict__ counts) {
  int t = blockIdx.x * blockDim.x + threadIdx.x;
  if (t >= T_TOKENS) return;
  const float* l = logits + (size_t)t * NEXP;
  float bv = l[0]; int be = 0;
#pragma unroll
  for (int e = 1; e < NEXP; ++e) {
    float v = l[e];
    if (v > bv) { bv = v; be = e; }   // strict > : first-max tiebreak like jnp.argmax
  }
  assign[t] = be;
  atomicAdd(&counts[be], 1);
}

// offsets + tile table (128-row tiles, shared by both gemms)
__global__ void k_scan(const int* __restrict__ counts,
                       int* __restrict__ offsets,
                       int* __restrict__ tile_e,
                       int* __restrict__ tile_rb,
                       int* __restrict__ ntiles) {
  if (threadIdx.x == 0) {
    int acc = 0, nt = 0;
    for (int e = 0; e < NEXP; ++e) {
      offsets[e] = acc;
      int c = counts[e];
      acc += c;
      int t = (c + 127) >> 7;
      for (int i = 0; i < t; ++i) { tile_e[nt] = e; tile_rb[nt] = i; ++nt; }
    }
    ntiles[0] = nt;
  }
}

// fused: compute bucket slot for token (one block per token) + gather/cast row
__global__ void k_place_gather(const float* __restrict__ x,
                               const int* __restrict__ assign,
                               const int* __restrict__ offsets,
                               int* __restrict__ cursors,
                               int* __restrict__ perm,
                               unsigned short* __restrict__ xg) {
  const int t = blockIdx.x;
  __shared__ int slot_s;
  if (threadIdx.x == 0) {
    int e = assign[t];
    int pos = atomicAdd(&cursors[e], 1);
    int slot = offsets[e] + pos;
    perm[slot] = t;
    slot_s = slot;
  }
  __syncthreads();
  const int slot = slot_s;
  const float4* src = (const float4*)(x + (size_t)t * DDIM);
  ushort4* dst = (ushort4*)(xg + (size_t)slot * DDIM);
#pragma unroll
  for (int c = 0; c < 2; ++c) {
    int c4 = threadIdx.x + c * 256;
    float4 v = src[c4];
    ushort4 o;
    o.x = f2bf(v.x); o.y = f2bf(v.y); o.z = f2bf(v.z); o.w = f2bf(v.w);
    dst[c4] = o;
  }
}

// both weight casts in one grid-stride kernel
__global__ void k_cast2(const float* __restrict__ s1, const float* __restrict__ s2,
                        unsigned short* __restrict__ d1, unsigned short* __restrict__ d2,
                        int n4) {
  const int stride = gridDim.x * blockDim.x;
  for (int i = blockIdx.x * blockDim.x + threadIdx.x; i < 2 * n4; i += stride) {
    float4 v;
    if (i < n4) v = ((const float4*)s1)[i];
    else        v = ((const float4*)s2)[i - n4];
    ushort4 o;
    o.x = f2bf(v.x); o.y = f2bf(v.y); o.z = f2bf(v.z); o.w = f2bf(v.w);
    if (i < n4) ((ushort4*)d1)[i] = o;
    else        ((ushort4*)d2)[i - n4] = o;
  }
}

__device__ __forceinline__ void glds(const unsigned short* g, unsigned short* l) {
  __builtin_amdgcn_global_load_lds(
      (const __attribute__((address_space(1))) void*)g,
      (__attribute__((address_space(3))) void*)l, 16, 0, 0);
}

// Grouped GEMM, BM=128 x BN=256, BK=32. 4 waves (256 thr), wave grid 1M x 4N:
// each wave owns a 128x64 output tile (acc 8x4). This halves LDS reads/FLOP vs
// a 64x64 wave tile (23.4 vs 31.2 KB/MFLOP) -- R2 analysis showed the k-step is
// LDS-throughput-bound (measured ~1875 cyc/block-step ~= predicted LDS cost).
// No B duplication across waves; A slice read by all 4 waves.
// Ring-2 static LDS (48 KiB, no hipFuncSetAttribute), distance-2 prefetch,
// counted vmcnt(6) (never drained to 0 in the loop). Per k-step:
//   vmcnt(6); barrier            -> slice ks landed everywhere
//   ds_read 12 frags; lgkmcnt(0); sched_barrier
//   barrier                      -> all waves done reading buf[c]
//   issue 6 glds (slice ks+2 -> buf[c])
//   setprio(1); 32 MFMA; setprio(0)
// XOR k-chunk swizzle both-sides (pre-swizzled global src + swizzled ds_read).
template<bool FIRST>
__launch_bounds__(256, 2)
__global__ void k_gemm(const unsigned short* __restrict__ Ap,
                       const unsigned short* __restrict__ Bw,
                       unsigned short* __restrict__ Hout,
                       float* __restrict__ Out,
                       const int* __restrict__ offsets,
                       const int* __restrict__ counts,
                       const int* __restrict__ perm,
                       const int* __restrict__ tile_e,
                       const int* __restrict__ tile_rb,
                       const int* __restrict__ ntiles) {
  constexpr int K  = FIRST ? DDIM : FDIM;   // 2048 : 4096
  constexpr int N  = FIRST ? FDIM : DDIM;   // 4096 : 2048
  constexpr int NS = K / 32;                // 64 : 128

  const int ty = blockIdx.y;
  if (ty >= ntiles[0]) return;
  const int e   = tile_e[ty];
  const int rb  = tile_rb[ty] << 7;
  const int off = offsets[e];
  const int Me  = counts[e];
  const int cb  = blockIdx.x << 8;          // 256 output cols per block

  __shared__ unsigned short At[2][128 * 32];   // 2 x 8 KB
  __shared__ unsigned short Bt[2][256 * 32];   // 2 x 16 KB  (48 KiB total, static)

  const int tid  = threadIdx.x;
  const int wave = tid >> 6;                // 0..3 (N dimension)
  const int lane = tid & 63;

  // staging map: thread -> row r = s*64 + (tid>>2), k-chunk pos tid&3;
  // source pre-swizzle: global chunk = pos ^ ((r>>1)&3) = pos ^ ((tid>>3)&3)
  const int tq4 = tid >> 2;
  const int kd8 = (((tid & 3) ^ ((tid >> 3) & 3)) << 3);

  int ar0 = rb + tq4;      if (ar0 >= Me) ar0 = Me - 1;  // clamp ragged M
  int ar1 = rb + 64 + tq4; if (ar1 >= Me) ar1 = Me - 1;
  const unsigned short* gA0 = Ap + (size_t)(off + ar0) * K + kd8;
  const unsigned short* gA1 = Ap + (size_t)(off + ar1) * K + kd8;
  const unsigned short* gB  = Bw + (size_t)e * N * K + (size_t)(cb + tq4) * K + kd8;

  const int dA = wave * 512;   // wave-uniform LDS stage base (glds adds lane*16B)

  // prologue: issue slices 0,1 (6 glds each, oldest-first)
#pragma unroll
  for (int s = 0; s < 2; ++s) {
    glds(gA0 + s * 32, &At[s][dA]);
    glds(gA1 + s * 32, &At[s][2048 + dA]);
#pragma unroll
    for (int t = 0; t < 4; ++t)
      glds(gB + (size_t)t * 64 * K + s * 32, &Bt[s][t * 2048 + dA]);
  }

  // read-side fragment offsets (shorts), swizzled k-chunk
  const int kswz8 = (((lane >> 4) ^ ((lane >> 1) & 3)) << 3);
  const int abase = (lane & 15) * 32 + kswz8;
  const int bbase = wave * 2048 + (lane & 15) * 32 + kswz8;

  f32x4 acc[8][4] = {};

  for (int ks = 0; ks < NS; ++ks) {
    const int c = ks & 1;
    int ka = ks + 2; if (ka >= NS) ka -= NS;   // dummy wrap keeps vmcnt invariant
    const int ko = ka * 32;

    asm volatile("s_waitcnt vmcnt(6)" ::: "memory");   // slice ks landed (own wave)
    __builtin_amdgcn_s_barrier();                      // -> landed for all waves

    bf16x8 af[8], bf[4];
#pragma unroll
    for (int i = 0; i < 8; ++i) af[i] = *(const bf16x8*)&At[c][i * 512 + abase];
#pragma unroll
    for (int n = 0; n < 4; ++n) bf[n] = *(const bf16x8*)&Bt[c][n * 512 + bbase];
    asm volatile("s_waitcnt lgkmcnt(0)" ::: "memory");
    __builtin_amdgcn_sched_barrier(0);
    __builtin_amdgcn_s_barrier();                      // all waves done reading buf[c]

    // overwrite buf[c] with slice ks+2 (safe after barrier above)
    glds(gA0 + ko, &At[c][dA]);
    glds(gA1 + ko, &At[c][2048 + dA]);
#pragma unroll
    for (int t = 0; t < 4; ++t)
      glds(gB + (size_t)t * 64 * K + ko, &Bt[c][t * 2048 + dA]);
    __builtin_amdgcn_sched_barrier(0);

    __builtin_amdgcn_s_setprio(1);
#pragma unroll
    for (int i = 0; i < 8; ++i)
#pragma unroll
      for (int n = 0; n < 4; ++n)
        acc[i][n] = __builtin_amdgcn_mfma_f32_16x16x32_bf16(af[i], bf[n], acc[i][n], 0, 0, 0);
    __builtin_amdgcn_s_setprio(0);
  }

  // epilogue: C/D layout col = lane&15, row = (lane>>4)*4 + reg
  const int ccol = lane & 15;
  const int cr0 = (lane >> 4) * 4;
  const int colbase = cb + wave * 64;
#pragma unroll
  for (int i = 0; i < 8; ++i) {
#pragma unroll
    for (int r = 0; r < 4; ++r) {
      int row = rb + i * 16 + cr0 + r;
      if (row < Me) {
        if constexpr (FIRST) {
          unsigned short* hrow = Hout + (size_t)(off + row) * N;
#pragma unroll
          for (int j = 0; j < 4; ++j) {
            float v = acc[i][j][r];
            float s = v / (1.0f + __expf(-v));   // silu
            hrow[colbase + j * 16 + ccol] = f2bf(s);
          }
        } else {
          int tok = perm[off + row];
          float* orow = Out + (size_t)tok * N;
#pragma unroll
          for (int j = 0; j < 4; ++j)
            orow[colbase + j * 16 + ccol] = acc[i][j][r];
        }
      }
    }
  }
}

extern "C" void kernel_launch(void* const* d_in, const int* in_sizes, int n_in,
                              void* d_out, int out_size, void* d_ws, size_t ws_size,
                              hipStream_t stream) {
  const float* x      = (const float*)d_in[0];   // [T, D] fp32
  const float* logits = (const float*)d_in[1];   // [T, E] fp32
  const float* w1     = (const float*)d_in[2];   // [E, F, D] fp32
  const float* w2     = (const float*)d_in[3];   // [E, D, F] fp32
  float* out = (float*)d_out;                    // [T, D] fp32

  char* ws = (char*)d_ws;
  int* counts  = (int*)(ws + 0);
  int* offsets = (int*)(ws + 64);
  int* cursors = (int*)(ws + 128);
  int* tile_e  = (int*)(ws + 256);    // 72 ints
  int* tile_rb = (int*)(ws + 1024);   // 72 ints
  int* ntiles  = (int*)(ws + 2048);
  int* assign  = (int*)(ws + 4096);
  int* perm    = (int*)(ws + 4096 + T_TOKENS * 4);
  size_t p = 4096 + (size_t)2 * T_TOKENS * 4;
  p = (p + 255) & ~(size_t)255;
  unsigned short* Xg  = (unsigned short*)(ws + p); p += (size_t)T_TOKENS * DDIM * 2;
  unsigned short* W1b = (unsigned short*)(ws + p); p += (size_t)NEXP * FDIM * DDIM * 2;
  unsigned short* W2b = (unsigned short*)(ws + p); p += (size_t)NEXP * DDIM * FDIM * 2;
  unsigned short* Hb  = (unsigned short*)(ws + p); p += (size_t)T_TOKENS * FDIM * 2;
  if (ws_size < p) return;  // ~369 MB required

  hipMemsetAsync(ws, 0, 4096, stream);  // counts + cursors + tables
  k_assign<<<T_TOKENS / 256, 256, 0, stream>>>(logits, assign, counts);
  k_scan<<<1, 64, 0, stream>>>(counts, offsets, tile_e, tile_rb, ntiles);
  k_place_gather<<<T_TOKENS, 256, 0, stream>>>(x, assign, offsets, cursors, perm, Xg);
  int n4 = NEXP * FDIM * (DDIM / 4);
  k_cast2<<<2048, 256, 0, stream>>>(w1, w2, W1b, W2b, n4);
  k_gemm<true><<<dim3(FDIM / 256, MAXTILES), 256, 0, stream>>>(
      Xg, W1b, Hb, nullptr, offsets, counts, perm, tile_e, tile_rb, ntiles);
  k_gemm<false><<<dim3(DDIM / 256, MAXTILES), 256, 0, stream>>>(
      Hb, W2b, nullptr, out, offsets, counts, perm, tile_e, tile_rb, ntiles);
}